// Round 3
// baseline (637.863 us; speedup 1.0000x reference)
//
#include <hip/hip_runtime.h>
#include <hip/hip_fp16.h>

// GCN 2-layer, sort-free SpMM formulation.
// partition (EPB=4096, 512 thr, fused wave-shfl scans, LDS-staged coalesced
// writes, src-side byte staging for out-degree) ->
// transform1 (per bucket: src hist -> norm_src, h1 = (feat*ns)@W1, fp16) ->
// gather1 (per bucket: LDS [256][33] fp32 atomic accumulate over pack edges,
//          relu+norms+W2 epilogue -> h2 fp16) ->
// gather2 (per bucket: LDS [256][20] fp32 atomic accumulate, bias epilogue).
// No CSR array, no within-bucket sort: saves ~38 MB traffic + a whole kernel.
// (Resubmission of round-2 source: bench failed on container acquisition,
//  not on the kernel; audit found no hang/fault class. Need the data point.)

#define NB   391      // buckets = ceil(100000/256); bucket = id >> 8
#define CAPB 5504     // padded per-bucket edge capacity (avg 4092, +22 sigma)
#define EPB  4096     // edges per partition block (8/thread at 512 threads)

// --- pass 1: partition edges by dst-bucket (packed src|dlocal|weight) and
//     src-bucket (low byte only, for out-degree hist). LDS-staged so global
//     writes are coalesced runs. Wave-shfl scans (validated round 1). ---
__global__ __launch_bounds__(512) void partition_kernel(
        const int* __restrict__ src, const int* __restrict__ dst,
        const float* __restrict__ ew,
        int* __restrict__ g_cur_d, int* __restrict__ g_cur_s,
        int2* __restrict__ pack_part, unsigned char* __restrict__ src_part, int m) {
    __shared__ int hist_d[NB], hist_s[NB];
    __shared__ int lbase_d[NB], lbase_s[NB];
    __shared__ int gbase_d[NB], gbase_s[NB];
    __shared__ int cur_d[NB], cur_s[NB];
    __shared__ int woffd[8], woffs[8];
    __shared__ long stage[EPB];            // 32 KB
    __shared__ unsigned short dbuck[EPB];  // 8 KB
    __shared__ unsigned char  sstage[EPB]; // 4 KB
    __shared__ unsigned short sbuck[EPB];  // 8 KB
    int t = threadIdx.x, lane = t & 63, w = t >> 6;
    for (int i = t; i < NB; i += 512) {
        hist_d[i] = 0; hist_s[i] = 0; cur_d[i] = 0; cur_s[i] = 0;
    }
    __syncthreads();
    int base_e = blockIdx.x * EPB;
    int total = m - base_e; if (total > EPB) total = EPB;
    int es[8], ed[8]; float wv[8];
#pragma unroll
    for (int k = 0; k < 8; k++) {
        int e = base_e + k * 512 + t;
        if (e < m) { es[k] = src[e]; ed[k] = dst[e]; wv[k] = ew[e]; }
        else ed[k] = -1;
    }
#pragma unroll
    for (int k = 0; k < 8; k++) {
        if (ed[k] >= 0) {
            atomicAdd(&hist_d[ed[k] >> 8], 1);
            atomicAdd(&hist_s[es[k] >> 8], 1);
        }
    }
    __syncthreads();
    // fused exclusive scans of hist_d/hist_s (NB=391) via wave shfl (3 barriers)
    int hvd = (t < NB) ? hist_d[t] : 0;
    int hvs = (t < NB) ? hist_s[t] : 0;
    int vd = hvd, vs = hvs;
#pragma unroll
    for (int off = 1; off < 64; off <<= 1) {
        int ud = __shfl_up(vd, off, 64);
        int us = __shfl_up(vs, off, 64);
        if (lane >= off) { vd += ud; vs += us; }
    }
    if (lane == 63) { woffd[w] = vd; woffs[w] = vs; }
    __syncthreads();
    if (t < 64) {                   // wave 0 scans the 8 wave totals
        int sd = (t < 8) ? woffd[t] : 0;
        int ss = (t < 8) ? woffs[t] : 0;
        int od = sd, os = ss;
#pragma unroll
        for (int off = 1; off < 8; off <<= 1) {
            int ud = __shfl_up(sd, off, 64);
            int us = __shfl_up(ss, off, 64);
            if (lane >= off) { sd += ud; ss += us; }
        }
        if (t < 8) { woffd[t] = sd - od; woffs[t] = ss - os; }
    }
    __syncthreads();
    if (t < NB) {
        lbase_d[t] = vd + woffd[w] - hvd;
        lbase_s[t] = vs + woffs[w] - hvs;
    }
    // reserve global space per bucket
    for (int i = t; i < NB; i += 512) {
        int c = hist_d[i];
        gbase_d[i] = i * CAPB + (c ? atomicAdd(&g_cur_d[i], c) : 0);
        c = hist_s[i];
        gbase_s[i] = i * CAPB + (c ? atomicAdd(&g_cur_s[i], c) : 0);
    }
    __syncthreads();
    // scatter into LDS stage, grouped by bucket
#pragma unroll
    for (int k = 0; k < 8; k++) {
        if (ed[k] >= 0) {
            int d = ed[k], s = es[k];
            int bd = d >> 8;
            int r = atomicAdd(&cur_d[bd], 1);
            int pos = lbase_d[bd] + r;
            stage[pos] = (long)(unsigned int)(s | ((d & 255) << 20)) |
                         ((long)__float_as_int(wv[k]) << 32);
            dbuck[pos] = (unsigned short)bd;
            int bs = s >> 8;
            int rs = atomicAdd(&cur_s[bs], 1);
            int ps = lbase_s[bs] + rs;
            sstage[ps] = (unsigned char)(s & 255);
            sbuck[ps] = (unsigned short)bs;
        }
    }
    __syncthreads();
    // stream out: consecutive slots in a bucket -> consecutive global addrs
    long* packl = (long*)pack_part;
    for (int i = t; i < total; i += 512) {
        int b = dbuck[i];
        packl[(size_t)gbase_d[b] + (i - lbase_d[b])] = stage[i];
    }
    for (int i = t; i < total; i += 512) {
        int b = sbuck[i];
        src_part[(size_t)gbase_s[b] + (i - lbase_s[b])] = sstage[i];
    }
}

// --- per bucket: out-degree hist -> norm_src; h1 = (feat*ns) @ W1 (fp16) ---
__global__ __launch_bounds__(1024) void transform1_kernel(
        const unsigned char* __restrict__ src_part, const int* __restrict__ g_cur_s,
        const float* __restrict__ feat, const float* __restrict__ W1,
        float* __restrict__ norm_src, __half* __restrict__ h1, int n) {
    __shared__ int cnt_s[256];
    __shared__ float nsrc[256];
    __shared__ float sW1[1024];
    __shared__ __align__(16) float sF[256 * 36];  // stride 36: float4-aligned, conflict-free
    int t = threadIdx.x, b = blockIdx.x;
    if (t < 256) cnt_s[t] = 0;
    sW1[t] = W1[t];
    __syncthreads();
    int count_s = g_cur_s[b]; if (count_s > CAPB) count_s = CAPB;
    const unsigned char* sp = src_part + (size_t)b * CAPB;
    for (int e = t; e < count_s; e += 1024) atomicAdd(&cnt_s[sp[e]], 1);
    __syncthreads();
    int node0 = b * 256;
    if (t < 256) {
        int node = node0 + t;
        if (node < n) {
            int ds = cnt_s[t];
            float ns = rsqrtf((float)(ds > 1 ? ds : 1));
            nsrc[t] = ns;
            norm_src[node] = ns;
        } else nsrc[t] = 0.0f;
    }
    __syncthreads();
    int lim = n - node0; if (lim > 256) lim = 256; if (lim < 0) lim = 0;
    const float4* f4 = (const float4*)feat;
    for (int o = t; o < lim * 8; o += 1024) {
        int i = o >> 3, k4 = o & 7;
        float4 vv = f4[(size_t)node0 * 8 + o];
        float ns = nsrc[i];
        vv.x *= ns; vv.y *= ns; vv.z *= ns; vv.w *= ns;
        ((float4*)(sF + i * 36))[k4] = vv;
    }
    __syncthreads();
    __half2* h1v = (__half2*)h1;
    for (int o = t; o < lim * 16; o += 1024) {
        int i = o >> 4, cp = o & 15;
        float a0 = 0.0f, a1 = 0.0f;
#pragma unroll
        for (int k = 0; k < 32; k++) {
            float x = sF[i * 36 + k];
            a0 += x * sW1[k * 32 + 2 * cp];
            a1 += x * sW1[k * 32 + 2 * cp + 1];
        }
        h1v[(size_t)(node0 + i) * 16 + cp] = __floats2half2_rn(a0, a1);
    }
}

// --- layer-1 SpMM per bucket: 4 lanes/edge, ds_add_f32 into acc[256][33];
//     epilogue: in-degree norms + bias + relu + norm_src, then @W2 -> h2. ---
__global__ __launch_bounds__(1024) void gather1_kernel(
        const int2* __restrict__ pack_part, const int* __restrict__ g_cur_d,
        const __half* __restrict__ h1, const float* __restrict__ norm_src,
        const float* __restrict__ W2, const float* __restrict__ b1,
        float* __restrict__ norm_dst, __half* __restrict__ h2, int n) {
    __shared__ float acc[256 * 33];    // stride 33: atomics & reads conflict-free
    __shared__ int cnt[256];
    __shared__ float sW2[512];
    __shared__ float sB1[32];
    __shared__ float sndv[256], snsv[256];
    int t = threadIdx.x, b = blockIdx.x;
    for (int i = t; i < 256 * 33; i += 1024) acc[i] = 0.0f;
    if (t < 256) cnt[t] = 0;
    if (t < 512) sW2[t] = W2[t];
    else if (t < 544) sB1[t - 512] = b1[t - 512];
    __syncthreads();
    int count = g_cur_d[b]; if (count > CAPB) count = CAPB;
    const int2* p = pack_part + (size_t)b * CAPB;
    const float4* h1f4 = (const float4*)h1;
    int eq = t >> 2, q = t & 3;        // 256 edges in flight; lane owns 8 dims
    for (int e0 = 0; e0 < count; e0 += 256) {
        int e = e0 + eq;
        if (e < count) {
            int2 v = p[e];
            int s  = v.x & 0x1FFFF;
            int dl = (v.x >> 20) & 255;
            float wgt = __int_as_float(v.y);
            if (q == 0) atomicAdd(&cnt[dl], 1);
            float4 r = h1f4[(size_t)s * 4 + q];   // 8 halves = dims 8q..8q+7
            float* ap = acc + dl * 33 + 8 * q;
            const __half2* hp = (const __half2*)&r;
#pragma unroll
            for (int j = 0; j < 4; j++) {
                float2 f = __half22float2(hp[j]);
                atomicAdd(ap + 2 * j,     f.x * wgt);
                atomicAdd(ap + 2 * j + 1, f.y * wgt);
            }
        }
    }
    __syncthreads();
    int node0 = b * 256;
    int lim = n - node0; if (lim > 256) lim = 256; if (lim < 0) lim = 0;
    if (t < 256) {
        int c0 = cnt[t];
        float nd = rsqrtf((float)(c0 > 1 ? c0 : 1));
        sndv[t] = nd;
        snsv[t] = (t < lim) ? norm_src[node0 + t] : 0.0f;
        if (t < lim) norm_dst[node0 + t] = nd;
    }
    __syncthreads();
    // x = relu(agg*nd + b1) * ns, in place
    for (int o = t; o < lim * 32; o += 1024) {
        int i = o >> 5, k = o & 31;
        float x = fmaxf(acc[i * 33 + k] * sndv[i] + sB1[k], 0.0f) * snsv[i];
        acc[i * 33 + k] = x;
    }
    __syncthreads();
    __half2* h2v = (__half2*)h2;
    for (int o = t; o < lim * 8; o += 1024) {
        int i = o >> 3, cp = o & 7;
        float a0 = 0.0f, a1 = 0.0f;
#pragma unroll
        for (int k = 0; k < 32; k++) {
            float x = acc[i * 33 + k];
            a0 += x * sW2[k * 16 + 2 * cp];
            a1 += x * sW2[k * 16 + 2 * cp + 1];
        }
        h2v[(size_t)(node0 + i) * 8 + cp] = __floats2half2_rn(a0, a1);
    }
}

// --- layer-2 SpMM per bucket: 2 lanes/edge, ds_add_f32 into acc[256][20];
//     epilogue: *norm_dst + b2 -> float4 store. ---
__global__ __launch_bounds__(1024) void gather2_kernel(
        const int2* __restrict__ pack_part, const int* __restrict__ g_cur_d,
        const __half* __restrict__ h2, const float* __restrict__ norm_dst,
        const float* __restrict__ b2, float* __restrict__ out, int n) {
    __shared__ __align__(16) float acc[256 * 20];  // stride 20: float4-aligned rows
    __shared__ float sB2[16];
    int t = threadIdx.x, b = blockIdx.x;
    for (int i = t; i < 256 * 20; i += 1024) acc[i] = 0.0f;
    if (t < 16) sB2[t] = b2[t];
    __syncthreads();
    int count = g_cur_d[b]; if (count > CAPB) count = CAPB;
    const int2* p = pack_part + (size_t)b * CAPB;
    const float4* h2f4 = (const float4*)h2;
    int eq = t >> 1, q = t & 1;        // 512 edges in flight; lane owns 8 dims
    for (int e0 = 0; e0 < count; e0 += 512) {
        int e = e0 + eq;
        if (e < count) {
            int2 v = p[e];
            int s  = v.x & 0x1FFFF;
            int dl = (v.x >> 20) & 255;
            float wgt = __int_as_float(v.y);
            float4 r = h2f4[(size_t)s * 2 + q];   // 8 halves = dims 8q..8q+7
            float* ap = acc + dl * 20 + 8 * q;
            const __half2* hp = (const __half2*)&r;
#pragma unroll
            for (int j = 0; j < 4; j++) {
                float2 f = __half22float2(hp[j]);
                atomicAdd(ap + 2 * j,     f.x * wgt);
                atomicAdd(ap + 2 * j + 1, f.y * wgt);
            }
        }
    }
    __syncthreads();
    int node0 = b * 256;
    int lim = n - node0; if (lim > 256) lim = 256; if (lim < 0) lim = 0;
    float4* out4 = (float4*)out;
    for (int o = t; o < lim * 4; o += 1024) {
        int i = o >> 2, q2 = o & 3;
        float nd = norm_dst[node0 + i];
        float4 a = *(const float4*)(acc + i * 20 + 4 * q2);
        a.x = a.x * nd + sB2[4 * q2];
        a.y = a.y * nd + sB2[4 * q2 + 1];
        a.z = a.z * nd + sB2[4 * q2 + 2];
        a.w = a.w * nd + sB2[4 * q2 + 3];
        out4[(size_t)(node0 + i) * 4 + q2] = a;
    }
}

extern "C" void kernel_launch(void* const* d_in, const int* in_sizes, int n_in,
                              void* d_out, int out_size, void* d_ws, size_t ws_size,
                              hipStream_t stream) {
    const float* feat = (const float*)d_in[0];
    const int*   src  = (const int*)d_in[1];
    const int*   dst  = (const int*)d_in[2];
    const float* ew   = (const float*)d_in[3];
    const float* W1   = (const float*)d_in[4];
    const float* b1   = (const float*)d_in[5];
    const float* W2   = (const float*)d_in[6];
    const float* b2   = (const float*)d_in[7];
    float* out = (float*)d_out;

    const int n = in_sizes[0] / 32;  // 100000
    const int m = in_sizes[1];       // 1600000

    // ws: pack_part[NB*CAPB int2] | h1 half[32n] | h2 half[16n] |
    //     norm_src[n] | norm_dst[n] | g_cur_d[NB] | g_cur_s[NB] |
    //     src_part uchar[NB*CAPB]
    char* wsb = (char*)d_ws;
    int2*   pack_part = (int2*)wsb;
    __half* h1        = (__half*)(pack_part + (size_t)NB * CAPB);
    __half* h2        = h1 + 32 * (size_t)n;
    float*  norm_src  = (float*)(h2 + 16 * (size_t)n);
    float*  norm_dst  = norm_src + n;
    int*    g_cur_d   = (int*)(norm_dst + n);
    int*    g_cur_s   = g_cur_d + NB;
    unsigned char* src_part = (unsigned char*)(g_cur_s + NB);

    hipMemsetAsync(g_cur_d, 0, 2 * NB * sizeof(int), stream);

    partition_kernel<<<(m + EPB - 1) / EPB, 512, 0, stream>>>(src, dst, ew, g_cur_d, g_cur_s,
                                                              pack_part, src_part, m);
    transform1_kernel<<<NB, 1024, 0, stream>>>(src_part, g_cur_s, feat, W1, norm_src, h1, n);
    gather1_kernel<<<NB, 1024, 0, stream>>>(pack_part, g_cur_d, h1, norm_src, W2, b1,
                                            norm_dst, h2, n);
    gather2_kernel<<<NB, 1024, 0, stream>>>(pack_part, g_cur_d, h2, norm_dst, b2, out, n);
}

// Round 4
// 187.117 us; speedup vs baseline: 3.4089x; 3.4089x over previous
//
#include <hip/hip_runtime.h>
#include <hip/hip_fp16.h>

// GCN 2-layer. Round-0 architecture (measured 186.9us) + surgical fixes:
// (a) gather1 sX stride 33 (kills 8-way LDS bank conflict on write+read),
// (b) wave-shfl scans in partition (fused dual) and csr (wave-0), replacing
//     ping-pong scans (~30 block barriers removed). Both validated r1/r3.
// partition (EPB=4096, 512 thr, LDS-staged coalesced writes) ->
// csr+norms+transform1 fused (1024 thr) -> gather1 (8 nodes/wave, float2
// lanes) -> gather2 (16 nodes/wave, float2 lanes, float4 store). fp16 hidden.

#define NB   391      // buckets = ceil(100000/256); bucket = id >> 8
#define CAPB 5504     // padded per-bucket edge capacity (avg 4092, +22 sigma)
#define EPB  4096     // edges per partition block (8/thread at 512 threads)

__device__ __forceinline__ long nt_load_i64(const long* p) {
    return __builtin_nontemporal_load(p);
}

// --- pass 1: partition edges by dst-bucket; LDS-staged, coalesced run writes ---
__global__ __launch_bounds__(512) void partition_kernel(
        const int* __restrict__ src, const int* __restrict__ dst,
        const float* __restrict__ ew,
        int* __restrict__ g_cur_d, int* __restrict__ g_cur_s,
        int2* __restrict__ pack_part, unsigned char* __restrict__ src_part, int m) {
    __shared__ int hist_d[NB], hist_s[NB];
    __shared__ int lbase_d[NB], lbase_s[NB];
    __shared__ int gbase_d[NB], gbase_s[NB];
    __shared__ int cur_d[NB], cur_s[NB];
    __shared__ int woffd[8], woffs[8];
    __shared__ long stage[EPB];            // 32 KB
    __shared__ unsigned short dbuck[EPB];  // 8 KB
    __shared__ unsigned char  sstage[EPB]; // 4 KB
    __shared__ unsigned short sbuck[EPB];  // 8 KB
    int t = threadIdx.x, lane = t & 63, w = t >> 6;
    for (int i = t; i < NB; i += 512) {
        hist_d[i] = 0; hist_s[i] = 0; cur_d[i] = 0; cur_s[i] = 0;
    }
    __syncthreads();
    int base_e = blockIdx.x * EPB;
    int total = m - base_e; if (total > EPB) total = EPB;
    int es[8], ed[8]; float wv[8];
#pragma unroll
    for (int k = 0; k < 8; k++) {
        int e = base_e + k * 512 + t;
        if (e < m) { es[k] = src[e]; ed[k] = dst[e]; wv[k] = ew[e]; }
        else ed[k] = -1;
    }
#pragma unroll
    for (int k = 0; k < 8; k++) {
        if (ed[k] >= 0) {
            atomicAdd(&hist_d[ed[k] >> 8], 1);
            atomicAdd(&hist_s[es[k] >> 8], 1);
        }
    }
    __syncthreads();
    // fused exclusive scans of hist_d/hist_s (NB=391) via wave shfl (3 barriers)
    int hvd = (t < NB) ? hist_d[t] : 0;
    int hvs = (t < NB) ? hist_s[t] : 0;
    int vd = hvd, vs = hvs;
#pragma unroll
    for (int off = 1; off < 64; off <<= 1) {
        int ud = __shfl_up(vd, off, 64);
        int us = __shfl_up(vs, off, 64);
        if (lane >= off) { vd += ud; vs += us; }
    }
    if (lane == 63) { woffd[w] = vd; woffs[w] = vs; }
    __syncthreads();
    if (t < 64) {                   // wave 0 scans the 8 wave totals
        int sd = (t < 8) ? woffd[t] : 0;
        int ss = (t < 8) ? woffs[t] : 0;
        int od = sd, os = ss;
#pragma unroll
        for (int off = 1; off < 8; off <<= 1) {
            int ud = __shfl_up(sd, off, 64);
            int us = __shfl_up(ss, off, 64);
            if (lane >= off) { sd += ud; ss += us; }
        }
        if (t < 8) { woffd[t] = sd - od; woffs[t] = ss - os; }
    }
    __syncthreads();
    if (t < NB) {
        lbase_d[t] = vd + woffd[w] - hvd;
        lbase_s[t] = vs + woffs[w] - hvs;
    }
    // reserve global space per bucket
    for (int i = t; i < NB; i += 512) {
        int c = hist_d[i];
        gbase_d[i] = i * CAPB + (c ? atomicAdd(&g_cur_d[i], c) : 0);
        c = hist_s[i];
        gbase_s[i] = i * CAPB + (c ? atomicAdd(&g_cur_s[i], c) : 0);
    }
    __syncthreads();
    // scatter into LDS stage, grouped by bucket
#pragma unroll
    for (int k = 0; k < 8; k++) {
        if (ed[k] >= 0) {
            int d = ed[k], s = es[k];
            int bd = d >> 8;
            int r = atomicAdd(&cur_d[bd], 1);
            int pos = lbase_d[bd] + r;
            stage[pos] = (long)(unsigned int)(s | ((d & 255) << 20)) |
                         ((long)__float_as_int(wv[k]) << 32);
            dbuck[pos] = (unsigned short)bd;
            int bs = s >> 8;
            int rs = atomicAdd(&cur_s[bs], 1);
            int ps = lbase_s[bs] + rs;
            sstage[ps] = (unsigned char)(s & 255);
            sbuck[ps] = (unsigned short)bs;
        }
    }
    __syncthreads();
    // stream out: consecutive slots in a bucket -> consecutive global addrs
    long* packl = (long*)pack_part;
    for (int i = t; i < total; i += 512) {
        int b = dbuck[i];
        packl[(size_t)gbase_d[b] + (i - lbase_d[b])] = stage[i];
    }
    for (int i = t; i < total; i += 512) {
        int b = sbuck[i];
        src_part[(size_t)gbase_s[b] + (i - lbase_s[b])] = sstage[i];
    }
}

// --- per bucket (1024 threads): dst CSR (hist + wave-0 scan + scatter in LDS)
//     + both norms + fused transform1 for this bucket's 256 nodes. ---
__global__ __launch_bounds__(1024) void csr_kernel(
                           const int2* __restrict__ pack_part,
                           const unsigned char* __restrict__ src_part,
                           const int* __restrict__ g_cur_d, const int* __restrict__ g_cur_s,
                           const float* __restrict__ feat, const float* __restrict__ W1,
                           int2* __restrict__ csr, int2* __restrict__ rs_cnt,
                           float* __restrict__ norm_src, float* __restrict__ norm_dst,
                           __half* __restrict__ h1, int n) {
    __shared__ int cnt[256];
    __shared__ int rowx[256];
    __shared__ int cur[256];
    __shared__ int cnt_s[256];
    __shared__ float nsrc[256];
    __shared__ float sW1[1024];
    extern __shared__ int2 stage[];  // CAPB entries (44 KB), reused as fp32 tile later
    int t = threadIdx.x, b = blockIdx.x;
    if (t < 256) { cnt[t] = 0; cur[t] = 0; cnt_s[t] = 0; }
    sW1[t] = W1[t];
    __syncthreads();
    int count = g_cur_d[b]; if (count > CAPB) count = CAPB;
    int count_s = g_cur_s[b]; if (count_s > CAPB) count_s = CAPB;
    const int2* p = pack_part + (size_t)b * CAPB;
    const unsigned char* sp = src_part + (size_t)b * CAPB;
    for (int e = t; e < count; e += 1024) atomicAdd(&cnt[p[e].x >> 20], 1);
    for (int e = t; e < count_s; e += 1024) atomicAdd(&cnt_s[sp[e]], 1);
    __syncthreads();
    if (t < 256) {
        int node = b * 256 + t;
        if (node < n) {
            int cs = cnt_s[t];
            float ns = rsqrtf((float)(cs > 1 ? cs : 1));
            nsrc[t] = ns;
            norm_src[node] = ns;
        } else nsrc[t] = 0.0f;
    }
    // wave 0: exclusive scan of cnt[256], 4 items/lane + shfl scan (1 barrier)
    if (t < 64) {
        int c0 = cnt[t * 4], c1 = cnt[t * 4 + 1], c2 = cnt[t * 4 + 2], c3 = cnt[t * 4 + 3];
        int tot = c0 + c1 + c2 + c3;
        int incl = tot;
#pragma unroll
        for (int off = 1; off < 64; off <<= 1) {
            int u = __shfl_up(incl, off, 64);
            if (t >= off) incl += u;
        }
        int excl = incl - tot;
        rowx[t * 4]     = excl;
        rowx[t * 4 + 1] = excl + c0;
        rowx[t * 4 + 2] = excl + c0 + c1;
        rowx[t * 4 + 3] = excl + c0 + c1 + c2;
    }
    __syncthreads();
    if (t < 256) {
        int node = b * 256 + t;
        if (node < n) {
            rs_cnt[node] = make_int2(b * CAPB + rowx[t], cnt[t]);
            norm_dst[node] = rsqrtf((float)(cnt[t] > 1 ? cnt[t] : 1));
        }
    }
    __syncthreads();
    for (int e = t; e < count; e += 1024) {
        int2 v = p[e];
        int dl = v.x >> 20;
        int r = atomicAdd(&cur[dl], 1);
        stage[rowx[dl] + r] = make_int2(v.x & 0x1FFFF, v.y);
    }
    __syncthreads();
    int2* outp = csr + (size_t)b * CAPB;
    for (int e = t; e < count; e += 1024) outp[e] = stage[e];
    __syncthreads();
    // fused transform1: reuse stage as float tile sF[256][32] (32 KB)
    float* sF = (float*)stage;
    int node0 = b * 256;
    int lim = n - node0; if (lim > 256) lim = 256; if (lim < 0) lim = 0;
    for (int o = t; o < lim * 32; o += 1024) {
        int i = o >> 5, k = o & 31;
        sF[o] = feat[(size_t)(node0 + i) * 32 + k] * nsrc[i];
    }
    __syncthreads();
    for (int o = t; o < lim * 32; o += 1024) {
        int i = o >> 5, col = o & 31;
        float acc = 0.0f;
#pragma unroll
        for (int k = 0; k < 32; k++) acc += sF[i * 32 + k] * sW1[k * 32 + col];
        h1[(size_t)(node0 + i) * 32 + col] = __float2half(acc);
    }
}

// --- gather1 + fused transform2: 8 nodes per wave (8 lanes each, lane owns
//     4 dims via one float2(=2xhalf2) load) -> 32 indep chains/wave.
//     sX stride 33: bank = (q*33+k)%32 spreads q -> conflict-free. ---
__global__ void gather1_fused_kernel(const __half* __restrict__ h1, const int2* __restrict__ csr,
                                     const int2* __restrict__ rs_cnt,
                                     const float* __restrict__ norm_src, const float* __restrict__ norm_dst,
                                     const float* __restrict__ W2, const float* __restrict__ b1,
                                     __half* __restrict__ h2, int n) {
    __shared__ float sW2[32 * 16];
    __shared__ float sB1[32];
    __shared__ float sX[4][8][33];
    int t = threadIdx.x;
    for (int i = t; i < 512; i += 256) sW2[i] = W2[i];
    if (t < 32) sB1[t] = b1[t];
    __syncthreads();
    int w = t >> 6, lane = t & 63;
    int q = lane >> 3;      // sub-node within wave (0..7)
    int dq = lane & 7;      // float2 index (dims 4dq..4dq+3)
    int node = (blockIdx.x * 4 + w) * 8 + q;
    bool valid = node < n;
    int2 rc = valid ? rs_cnt[node] : make_int2(0, 0);
    long base = rc.x;
    int c = rc.y;
    const float2* tv = (const float2*)h1;   // 8 float2 (32 halves) per row
    const long* csrl = (const long*)csr;
    float a00=0,a01=0,a02=0,a03=0, a10=0,a11=0,a12=0,a13=0;
    float a20=0,a21=0,a22=0,a23=0, a30=0,a31=0,a32=0,a33=0;
    int j = 0;
    for (; j + 3 < c; j += 4) {
        long q0 = nt_load_i64(csrl + base + j);
        long q1 = nt_load_i64(csrl + base + j + 1);
        long q2 = nt_load_i64(csrl + base + j + 2);
        long q3 = nt_load_i64(csrl + base + j + 3);
        float2 r0 = tv[(size_t)((int)q0 & 0xFFFFF) * 8 + dq];
        float2 r1 = tv[(size_t)((int)q1 & 0xFFFFF) * 8 + dq];
        float2 r2 = tv[(size_t)((int)q2 & 0xFFFFF) * 8 + dq];
        float2 r3 = tv[(size_t)((int)q3 & 0xFFFFF) * 8 + dq];
        float w0 = __int_as_float((int)(q0 >> 32)), w1 = __int_as_float((int)(q1 >> 32));
        float w2 = __int_as_float((int)(q2 >> 32)), w3 = __int_as_float((int)(q3 >> 32));
        float2 l0 = __half22float2(*(__half2*)&r0.x), h0 = __half22float2(*(__half2*)&r0.y);
        float2 l1 = __half22float2(*(__half2*)&r1.x), h1v = __half22float2(*(__half2*)&r1.y);
        float2 l2 = __half22float2(*(__half2*)&r2.x), h2v = __half22float2(*(__half2*)&r2.y);
        float2 l3 = __half22float2(*(__half2*)&r3.x), h3v = __half22float2(*(__half2*)&r3.y);
        a00 += l0.x * w0; a01 += l0.y * w0; a02 += h0.x * w0; a03 += h0.y * w0;
        a10 += l1.x * w1; a11 += l1.y * w1; a12 += h1v.x * w1; a13 += h1v.y * w1;
        a20 += l2.x * w2; a21 += l2.y * w2; a22 += h2v.x * w2; a23 += h2v.y * w2;
        a30 += l3.x * w3; a31 += l3.y * w3; a32 += h3v.x * w3; a33 += h3v.y * w3;
    }
    for (; j < c; j++) {
        long qq = nt_load_i64(csrl + base + j);
        float2 r = tv[(size_t)((int)qq & 0xFFFFF) * 8 + dq];
        float ww = __int_as_float((int)(qq >> 32));
        float2 l = __half22float2(*(__half2*)&r.x), h = __half22float2(*(__half2*)&r.y);
        a00 += l.x * ww; a01 += l.y * ww; a02 += h.x * ww; a03 += h.y * ww;
    }
    float s0 = (a00 + a10) + (a20 + a30);
    float s1 = (a01 + a11) + (a21 + a31);
    float s2 = (a02 + a12) + (a22 + a32);
    float s3 = (a03 + a13) + (a23 + a33);
    if (valid) {
        float nd = norm_dst[node], ns = norm_src[node];
        int d0 = 4 * dq;
        sX[w][q][d0]     = fmaxf(s0 * nd + sB1[d0],     0.0f) * ns;
        sX[w][q][d0 + 1] = fmaxf(s1 * nd + sB1[d0 + 1], 0.0f) * ns;
        sX[w][q][d0 + 2] = fmaxf(s2 * nd + sB1[d0 + 2], 0.0f) * ns;
        sX[w][q][d0 + 3] = fmaxf(s3 * nd + sB1[d0 + 3], 0.0f) * ns;
    }
    // wave-synchronous LDS use (same wave wrote sX[w][q]); lane computes 2 cols
    if (valid) {
        float o0 = 0.0f, o1 = 0.0f;
        int c0 = 2 * dq, c1 = 2 * dq + 1;
#pragma unroll
        for (int k = 0; k < 32; k++) {
            float x = sX[w][q][k];
            o0 += x * sW2[k * 16 + c0];
            o1 += x * sW2[k * 16 + c1];
        }
        ((__half2*)h2)[(size_t)node * 8 + dq] = __floats2half2_rn(o0, o1);
    }
}

// --- gather2 + fused epilogue: 16 nodes per wave (4 lanes each, lane owns
//     4 dims via one float2 load) -> float4 store, no LDS. ---
__global__ void gather2_kernel(const __half* __restrict__ h2, const int2* __restrict__ csr,
                               const int2* __restrict__ rs_cnt,
                               const float* __restrict__ norm_dst, const float* __restrict__ b2,
                               float* __restrict__ out, int n) {
    int t = threadIdx.x;
    int w = t >> 6, lane = t & 63;
    int q = lane >> 2;     // sub-node within wave (0..15)
    int dq = lane & 3;     // float2 index (dims 4dq..4dq+3)
    int node = (blockIdx.x * 4 + w) * 16 + q;
    bool valid = node < n;
    int2 rc = valid ? rs_cnt[node] : make_int2(0, 0);
    long base = rc.x;
    int c = rc.y;
    const float2* tv = (const float2*)h2;   // 4 float2 (16 halves) per row
    const long* csrl = (const long*)csr;
    float a00=0,a01=0,a02=0,a03=0, a10=0,a11=0,a12=0,a13=0;
    float a20=0,a21=0,a22=0,a23=0, a30=0,a31=0,a32=0,a33=0;
    int j = 0;
    for (; j + 3 < c; j += 4) {
        long q0 = nt_load_i64(csrl + base + j);
        long q1 = nt_load_i64(csrl + base + j + 1);
        long q2 = nt_load_i64(csrl + base + j + 2);
        long q3 = nt_load_i64(csrl + base + j + 3);
        float2 r0 = tv[(size_t)((int)q0 & 0xFFFFF) * 4 + dq];
        float2 r1 = tv[(size_t)((int)q1 & 0xFFFFF) * 4 + dq];
        float2 r2 = tv[(size_t)((int)q2 & 0xFFFFF) * 4 + dq];
        float2 r3 = tv[(size_t)((int)q3 & 0xFFFFF) * 4 + dq];
        float w0 = __int_as_float((int)(q0 >> 32)), w1 = __int_as_float((int)(q1 >> 32));
        float w2 = __int_as_float((int)(q2 >> 32)), w3 = __int_as_float((int)(q3 >> 32));
        float2 l0 = __half22float2(*(__half2*)&r0.x), h0 = __half22float2(*(__half2*)&r0.y);
        float2 l1 = __half22float2(*(__half2*)&r1.x), h1v = __half22float2(*(__half2*)&r1.y);
        float2 l2 = __half22float2(*(__half2*)&r2.x), h2v = __half22float2(*(__half2*)&r2.y);
        float2 l3 = __half22float2(*(__half2*)&r3.x), h3v = __half22float2(*(__half2*)&r3.y);
        a00 += l0.x * w0; a01 += l0.y * w0; a02 += h0.x * w0; a03 += h0.y * w0;
        a10 += l1.x * w1; a11 += l1.y * w1; a12 += h1v.x * w1; a13 += h1v.y * w1;
        a20 += l2.x * w2; a21 += l2.y * w2; a22 += h2v.x * w2; a23 += h2v.y * w2;
        a30 += l3.x * w3; a31 += l3.y * w3; a32 += h3v.x * w3; a33 += h3v.y * w3;
    }
    for (; j < c; j++) {
        long qq = nt_load_i64(csrl + base + j);
        float2 r = tv[(size_t)((int)qq & 0xFFFFF) * 4 + dq];
        float ww = __int_as_float((int)(qq >> 32));
        float2 l = __half22float2(*(__half2*)&r.x), h = __half22float2(*(__half2*)&r.y);
        a00 += l.x * ww; a01 += l.y * ww; a02 += h.x * ww; a03 += h.y * ww;
    }
    if (valid) {
        float nd = norm_dst[node];
        int d0 = 4 * dq;
        float4 o;
        o.x = ((a00 + a10) + (a20 + a30)) * nd + b2[d0];
        o.y = ((a01 + a11) + (a21 + a31)) * nd + b2[d0 + 1];
        o.z = ((a02 + a12) + (a22 + a32)) * nd + b2[d0 + 2];
        o.w = ((a03 + a13) + (a23 + a33)) * nd + b2[d0 + 3];
        ((float4*)out)[(size_t)node * 4 + dq] = o;
    }
}

extern "C" void kernel_launch(void* const* d_in, const int* in_sizes, int n_in,
                              void* d_out, int out_size, void* d_ws, size_t ws_size,
                              hipStream_t stream) {
    const float* feat = (const float*)d_in[0];
    const int*   src  = (const int*)d_in[1];
    const int*   dst  = (const int*)d_in[2];
    const float* ew   = (const float*)d_in[3];
    const float* W1   = (const float*)d_in[4];
    const float* b1   = (const float*)d_in[5];
    const float* W2   = (const float*)d_in[6];
    const float* b2   = (const float*)d_in[7];
    float* out = (float*)d_out;

    const int n = in_sizes[0] / 32;  // 100000
    const int m = in_sizes[1];       // 1600000

    // ws: pack_part[NB*CAPB int2] | csr[NB*CAPB int2] | h1 half[32n] | h2 half[16n] |
    //     norm_src[n] | norm_dst[n] | rs_cnt int2[n] | g_cur_d[NB] | g_cur_s[NB] |
    //     src_part uchar[NB*CAPB]
    char* wsb = (char*)d_ws;
    int2*   pack_part = (int2*)wsb;
    int2*   csr       = pack_part + (size_t)NB * CAPB;
    __half* h1        = (__half*)(csr + (size_t)NB * CAPB);
    __half* h2        = h1 + 32 * (size_t)n;
    float*  norm_src  = (float*)(h2 + 16 * (size_t)n);
    float*  norm_dst  = norm_src + n;
    int2*   rs_cnt    = (int2*)(norm_dst + n);
    int*    g_cur_d   = (int*)(rs_cnt + n);
    int*    g_cur_s   = g_cur_d + NB;
    unsigned char* src_part = (unsigned char*)(g_cur_s + NB);

    hipMemsetAsync(g_cur_d, 0, 2 * NB * sizeof(int), stream);

    partition_kernel<<<(m + EPB - 1) / EPB, 512, 0, stream>>>(src, dst, ew, g_cur_d, g_cur_s,
                                                              pack_part, src_part, m);
    csr_kernel<<<NB, 1024, CAPB * sizeof(int2), stream>>>(pack_part, src_part, g_cur_d, g_cur_s,
                                                          feat, W1, csr, rs_cnt,
                                                          norm_src, norm_dst, h1, n);
    gather1_fused_kernel<<<(n + 31) / 32, 256, 0, stream>>>(h1, csr, rs_cnt,
                                                            norm_src, norm_dst, W2, b1, h2, n);
    gather2_kernel<<<(n + 63) / 64, 256, 0, stream>>>(h2, csr, rs_cnt, norm_dst, b2, out, n);
}

// Round 5
// 186.837 us; speedup vs baseline: 3.4140x; 1.0015x over previous
//
#include <hip/hip_runtime.h>
#include <hip/hip_fp16.h>

// GCN 2-layer. Round-0 architecture + validated-neutral fixes (sX stride 33,
// wave-shfl scans) + this round's levers:
//   (a) partition at 1024 threads: scatter chain 8->4 deep, all 391 blocks
//       co-resident (2/CU, 64.6 KB LDS), one dispatch round;
//   (b) csr register-caches pack entries (pk[4]) - no second 12.8 MB read.
// partition -> csr+norms+transform1 fused -> gather1 (8 nodes/wave) ->
// gather2 (16 nodes/wave, float4 store). fp16 hidden states.

#define NB   391      // buckets = ceil(100000/256); bucket = id >> 8
#define CAPB 5504     // padded per-bucket edge capacity (avg 4092, +22 sigma)
#define EPB  4096     // edges per partition block (4/thread at 1024 threads)

__device__ __forceinline__ long nt_load_i64(const long* p) {
    return __builtin_nontemporal_load(p);
}

// --- pass 1: partition edges by dst-bucket; LDS-staged, coalesced run writes ---
__global__ __launch_bounds__(1024) void partition_kernel(
        const int* __restrict__ src, const int* __restrict__ dst,
        const float* __restrict__ ew,
        int* __restrict__ g_cur_d, int* __restrict__ g_cur_s,
        int2* __restrict__ pack_part, unsigned char* __restrict__ src_part, int m) {
    __shared__ int hist_d[NB], hist_s[NB];
    __shared__ int lbase_d[NB], lbase_s[NB];
    __shared__ int gbase_d[NB], gbase_s[NB];
    __shared__ int cur_d[NB], cur_s[NB];
    __shared__ int woffd[16], woffs[16];
    __shared__ long stage[EPB];            // 32 KB
    __shared__ unsigned short dbuck[EPB];  // 8 KB
    __shared__ unsigned char  sstage[EPB]; // 4 KB
    __shared__ unsigned short sbuck[EPB];  // 8 KB
    int t = threadIdx.x, lane = t & 63, w = t >> 6;
    for (int i = t; i < NB; i += 1024) {
        hist_d[i] = 0; hist_s[i] = 0; cur_d[i] = 0; cur_s[i] = 0;
    }
    __syncthreads();
    int base_e = blockIdx.x * EPB;
    int total = m - base_e; if (total > EPB) total = EPB;
    int es[4], ed[4]; float wv[4];
#pragma unroll
    for (int k = 0; k < 4; k++) {
        int e = base_e + k * 1024 + t;
        if (e < m) { es[k] = src[e]; ed[k] = dst[e]; wv[k] = ew[e]; }
        else ed[k] = -1;
    }
#pragma unroll
    for (int k = 0; k < 4; k++) {
        if (ed[k] >= 0) {
            atomicAdd(&hist_d[ed[k] >> 8], 1);
            atomicAdd(&hist_s[es[k] >> 8], 1);
        }
    }
    __syncthreads();
    // fused exclusive scans of hist_d/hist_s (NB=391) via wave shfl (3 barriers)
    int hvd = (t < NB) ? hist_d[t] : 0;
    int hvs = (t < NB) ? hist_s[t] : 0;
    int vd = hvd, vs = hvs;
#pragma unroll
    for (int off = 1; off < 64; off <<= 1) {
        int ud = __shfl_up(vd, off, 64);
        int us = __shfl_up(vs, off, 64);
        if (lane >= off) { vd += ud; vs += us; }
    }
    if (lane == 63) { woffd[w] = vd; woffs[w] = vs; }   // waves >=7 write 0
    __syncthreads();
    if (t < 64) {                   // wave 0 scans the 16 wave totals
        int sd = (t < 16) ? woffd[t] : 0;
        int ss = (t < 16) ? woffs[t] : 0;
        int od = sd, os = ss;
#pragma unroll
        for (int off = 1; off < 16; off <<= 1) {
            int ud = __shfl_up(sd, off, 64);
            int us = __shfl_up(ss, off, 64);
            if (lane >= off) { sd += ud; ss += us; }
        }
        if (t < 16) { woffd[t] = sd - od; woffs[t] = ss - os; }
    }
    __syncthreads();
    if (t < NB) {
        lbase_d[t] = vd + woffd[w] - hvd;
        lbase_s[t] = vs + woffs[w] - hvs;
    }
    // reserve global space per bucket
    for (int i = t; i < NB; i += 1024) {
        int c = hist_d[i];
        gbase_d[i] = i * CAPB + (c ? atomicAdd(&g_cur_d[i], c) : 0);
        c = hist_s[i];
        gbase_s[i] = i * CAPB + (c ? atomicAdd(&g_cur_s[i], c) : 0);
    }
    __syncthreads();
    // scatter into LDS stage, grouped by bucket (4-deep serial chain)
#pragma unroll
    for (int k = 0; k < 4; k++) {
        if (ed[k] >= 0) {
            int d = ed[k], s = es[k];
            int bd = d >> 8;
            int r = atomicAdd(&cur_d[bd], 1);
            int pos = lbase_d[bd] + r;
            stage[pos] = (long)(unsigned int)(s | ((d & 255) << 20)) |
                         ((long)__float_as_int(wv[k]) << 32);
            dbuck[pos] = (unsigned short)bd;
            int bs = s >> 8;
            int rs = atomicAdd(&cur_s[bs], 1);
            int ps = lbase_s[bs] + rs;
            sstage[ps] = (unsigned char)(s & 255);
            sbuck[ps] = (unsigned short)bs;
        }
    }
    __syncthreads();
    // stream out: consecutive slots in a bucket -> consecutive global addrs
    long* packl = (long*)pack_part;
    for (int i = t; i < total; i += 1024) {
        int b = dbuck[i];
        packl[(size_t)gbase_d[b] + (i - lbase_d[b])] = stage[i];
    }
    for (int i = t; i < total; i += 1024) {
        int b = sbuck[i];
        src_part[(size_t)gbase_s[b] + (i - lbase_s[b])] = sstage[i];
    }
}

// --- per bucket (1024 threads): dst CSR (hist + wave-0 scan + scatter in LDS)
//     + both norms + fused transform1. pack entries register-cached (pk[4]). ---
__global__ __launch_bounds__(1024) void csr_kernel(
                           const int2* __restrict__ pack_part,
                           const unsigned char* __restrict__ src_part,
                           const int* __restrict__ g_cur_d, const int* __restrict__ g_cur_s,
                           const float* __restrict__ feat, const float* __restrict__ W1,
                           int2* __restrict__ csr, int2* __restrict__ rs_cnt,
                           float* __restrict__ norm_src, float* __restrict__ norm_dst,
                           __half* __restrict__ h1, int n) {
    __shared__ int cnt[256];
    __shared__ int rowx[256];
    __shared__ int cur[256];
    __shared__ int cnt_s[256];
    __shared__ float nsrc[256];
    __shared__ float sW1[1024];
    extern __shared__ int2 stage[];  // CAPB entries (44 KB), reused as fp32 tile later
    int t = threadIdx.x, b = blockIdx.x;
    if (t < 256) { cnt[t] = 0; cur[t] = 0; cnt_s[t] = 0; }
    sW1[t] = W1[t];
    __syncthreads();
    int count = g_cur_d[b]; if (count > CAPB) count = CAPB;
    int count_s = g_cur_s[b]; if (count_s > CAPB) count_s = CAPB;
    const int2* p = pack_part + (size_t)b * CAPB;
    const unsigned char* sp = src_part + (size_t)b * CAPB;
    int2 pk[4];
#pragma unroll
    for (int u = 0; u < 4; u++) {
        int e = t + u * 1024;
        if (e < count) { pk[u] = p[e]; atomicAdd(&cnt[pk[u].x >> 20], 1); }
    }
    for (int e = t + 4096; e < count; e += 1024)    // rare tail past 4096
        atomicAdd(&cnt[p[e].x >> 20], 1);
    for (int e = t; e < count_s; e += 1024) atomicAdd(&cnt_s[sp[e]], 1);
    __syncthreads();
    if (t < 256) {
        int node = b * 256 + t;
        if (node < n) {
            int cs = cnt_s[t];
            float ns = rsqrtf((float)(cs > 1 ? cs : 1));
            nsrc[t] = ns;
            norm_src[node] = ns;
        } else nsrc[t] = 0.0f;
    }
    // wave 0: exclusive scan of cnt[256], 4 items/lane + shfl scan (1 barrier)
    if (t < 64) {
        int c0 = cnt[t * 4], c1 = cnt[t * 4 + 1], c2 = cnt[t * 4 + 2], c3 = cnt[t * 4 + 3];
        int tot = c0 + c1 + c2 + c3;
        int incl = tot;
#pragma unroll
        for (int off = 1; off < 64; off <<= 1) {
            int u = __shfl_up(incl, off, 64);
            if (t >= off) incl += u;
        }
        int excl = incl - tot;
        rowx[t * 4]     = excl;
        rowx[t * 4 + 1] = excl + c0;
        rowx[t * 4 + 2] = excl + c0 + c1;
        rowx[t * 4 + 3] = excl + c0 + c1 + c2;
    }
    __syncthreads();
    if (t < 256) {
        int node = b * 256 + t;
        if (node < n) {
            rs_cnt[node] = make_int2(b * CAPB + rowx[t], cnt[t]);
            norm_dst[node] = rsqrtf((float)(cnt[t] > 1 ? cnt[t] : 1));
        }
    }
    __syncthreads();
#pragma unroll
    for (int u = 0; u < 4; u++) {
        int e = t + u * 1024;
        if (e < count) {
            int2 v = pk[u];
            int dl = v.x >> 20;
            int r = atomicAdd(&cur[dl], 1);
            stage[rowx[dl] + r] = make_int2(v.x & 0x1FFFF, v.y);
        }
    }
    for (int e = t + 4096; e < count; e += 1024) {
        int2 v = p[e];
        int dl = v.x >> 20;
        int r = atomicAdd(&cur[dl], 1);
        stage[rowx[dl] + r] = make_int2(v.x & 0x1FFFF, v.y);
    }
    __syncthreads();
    int2* outp = csr + (size_t)b * CAPB;
    for (int e = t; e < count; e += 1024) outp[e] = stage[e];
    __syncthreads();
    // fused transform1: reuse stage as float tile sF[256][32] (32 KB)
    float* sF = (float*)stage;
    int node0 = b * 256;
    int lim = n - node0; if (lim > 256) lim = 256; if (lim < 0) lim = 0;
    for (int o = t; o < lim * 32; o += 1024) {
        int i = o >> 5, k = o & 31;
        sF[o] = feat[(size_t)(node0 + i) * 32 + k] * nsrc[i];
    }
    __syncthreads();
    for (int o = t; o < lim * 32; o += 1024) {
        int i = o >> 5, col = o & 31;
        float acc = 0.0f;
#pragma unroll
        for (int k = 0; k < 32; k++) acc += sF[i * 32 + k] * sW1[k * 32 + col];
        h1[(size_t)(node0 + i) * 32 + col] = __float2half(acc);
    }
}

// --- gather1 + fused transform2: 8 nodes per wave (8 lanes each, lane owns
//     4 dims via one float2(=2xhalf2) load) -> 32 indep chains/wave.
//     sX stride 33: conflict-free (validated-neutral, kept). ---
__global__ void gather1_fused_kernel(const __half* __restrict__ h1, const int2* __restrict__ csr,
                                     const int2* __restrict__ rs_cnt,
                                     const float* __restrict__ norm_src, const float* __restrict__ norm_dst,
                                     const float* __restrict__ W2, const float* __restrict__ b1,
                                     __half* __restrict__ h2, int n) {
    __shared__ float sW2[32 * 16];
    __shared__ float sB1[32];
    __shared__ float sX[4][8][33];
    int t = threadIdx.x;
    for (int i = t; i < 512; i += 256) sW2[i] = W2[i];
    if (t < 32) sB1[t] = b1[t];
    __syncthreads();
    int w = t >> 6, lane = t & 63;
    int q = lane >> 3;      // sub-node within wave (0..7)
    int dq = lane & 7;      // float2 index (dims 4dq..4dq+3)
    int node = (blockIdx.x * 4 + w) * 8 + q;
    bool valid = node < n;
    int2 rc = valid ? rs_cnt[node] : make_int2(0, 0);
    long base = rc.x;
    int c = rc.y;
    const float2* tv = (const float2*)h1;   // 8 float2 (32 halves) per row
    const long* csrl = (const long*)csr;
    float a00=0,a01=0,a02=0,a03=0, a10=0,a11=0,a12=0,a13=0;
    float a20=0,a21=0,a22=0,a23=0, a30=0,a31=0,a32=0,a33=0;
    int j = 0;
    for (; j + 3 < c; j += 4) {
        long q0 = nt_load_i64(csrl + base + j);
        long q1 = nt_load_i64(csrl + base + j + 1);
        long q2 = nt_load_i64(csrl + base + j + 2);
        long q3 = nt_load_i64(csrl + base + j + 3);
        float2 r0 = tv[(size_t)((int)q0 & 0xFFFFF) * 8 + dq];
        float2 r1 = tv[(size_t)((int)q1 & 0xFFFFF) * 8 + dq];
        float2 r2 = tv[(size_t)((int)q2 & 0xFFFFF) * 8 + dq];
        float2 r3 = tv[(size_t)((int)q3 & 0xFFFFF) * 8 + dq];
        float w0 = __int_as_float((int)(q0 >> 32)), w1 = __int_as_float((int)(q1 >> 32));
        float w2 = __int_as_float((int)(q2 >> 32)), w3 = __int_as_float((int)(q3 >> 32));
        float2 l0 = __half22float2(*(__half2*)&r0.x), h0 = __half22float2(*(__half2*)&r0.y);
        float2 l1 = __half22float2(*(__half2*)&r1.x), h1v = __half22float2(*(__half2*)&r1.y);
        float2 l2 = __half22float2(*(__half2*)&r2.x), h2v = __half22float2(*(__half2*)&r2.y);
        float2 l3 = __half22float2(*(__half2*)&r3.x), h3v = __half22float2(*(__half2*)&r3.y);
        a00 += l0.x * w0; a01 += l0.y * w0; a02 += h0.x * w0; a03 += h0.y * w0;
        a10 += l1.x * w1; a11 += l1.y * w1; a12 += h1v.x * w1; a13 += h1v.y * w1;
        a20 += l2.x * w2; a21 += l2.y * w2; a22 += h2v.x * w2; a23 += h2v.y * w2;
        a30 += l3.x * w3; a31 += l3.y * w3; a32 += h3v.x * w3; a33 += h3v.y * w3;
    }
    for (; j < c; j++) {
        long qq = nt_load_i64(csrl + base + j);
        float2 r = tv[(size_t)((int)qq & 0xFFFFF) * 8 + dq];
        float ww = __int_as_float((int)(qq >> 32));
        float2 l = __half22float2(*(__half2*)&r.x), h = __half22float2(*(__half2*)&r.y);
        a00 += l.x * ww; a01 += l.y * ww; a02 += h.x * ww; a03 += h.y * ww;
    }
    float s0 = (a00 + a10) + (a20 + a30);
    float s1 = (a01 + a11) + (a21 + a31);
    float s2 = (a02 + a12) + (a22 + a32);
    float s3 = (a03 + a13) + (a23 + a33);
    if (valid) {
        float nd = norm_dst[node], ns = norm_src[node];
        int d0 = 4 * dq;
        sX[w][q][d0]     = fmaxf(s0 * nd + sB1[d0],     0.0f) * ns;
        sX[w][q][d0 + 1] = fmaxf(s1 * nd + sB1[d0 + 1], 0.0f) * ns;
        sX[w][q][d0 + 2] = fmaxf(s2 * nd + sB1[d0 + 2], 0.0f) * ns;
        sX[w][q][d0 + 3] = fmaxf(s3 * nd + sB1[d0 + 3], 0.0f) * ns;
    }
    // wave-synchronous LDS use (same wave wrote sX[w][q]); lane computes 2 cols
    if (valid) {
        float o0 = 0.0f, o1 = 0.0f;
        int c0 = 2 * dq, c1 = 2 * dq + 1;
#pragma unroll
        for (int k = 0; k < 32; k++) {
            float x = sX[w][q][k];
            o0 += x * sW2[k * 16 + c0];
            o1 += x * sW2[k * 16 + c1];
        }
        ((__half2*)h2)[(size_t)node * 8 + dq] = __floats2half2_rn(o0, o1);
    }
}

// --- gather2 + fused epilogue: 16 nodes per wave (4 lanes each, lane owns
//     4 dims via one float2 load) -> float4 store, no LDS. ---
__global__ void gather2_kernel(const __half* __restrict__ h2, const int2* __restrict__ csr,
                               const int2* __restrict__ rs_cnt,
                               const float* __restrict__ norm_dst, const float* __restrict__ b2,
                               float* __restrict__ out, int n) {
    int t = threadIdx.x;
    int w = t >> 6, lane = t & 63;
    int q = lane >> 2;     // sub-node within wave (0..15)
    int dq = lane & 3;     // float2 index (dims 4dq..4dq+3)
    int node = (blockIdx.x * 4 + w) * 16 + q;
    bool valid = node < n;
    int2 rc = valid ? rs_cnt[node] : make_int2(0, 0);
    long base = rc.x;
    int c = rc.y;
    const float2* tv = (const float2*)h2;   // 4 float2 (16 halves) per row
    const long* csrl = (const long*)csr;
    float a00=0,a01=0,a02=0,a03=0, a10=0,a11=0,a12=0,a13=0;
    float a20=0,a21=0,a22=0,a23=0, a30=0,a31=0,a32=0,a33=0;
    int j = 0;
    for (; j + 3 < c; j += 4) {
        long q0 = nt_load_i64(csrl + base + j);
        long q1 = nt_load_i64(csrl + base + j + 1);
        long q2 = nt_load_i64(csrl + base + j + 2);
        long q3 = nt_load_i64(csrl + base + j + 3);
        float2 r0 = tv[(size_t)((int)q0 & 0xFFFFF) * 4 + dq];
        float2 r1 = tv[(size_t)((int)q1 & 0xFFFFF) * 4 + dq];
        float2 r2 = tv[(size_t)((int)q2 & 0xFFFFF) * 4 + dq];
        float2 r3 = tv[(size_t)((int)q3 & 0xFFFFF) * 4 + dq];
        float w0 = __int_as_float((int)(q0 >> 32)), w1 = __int_as_float((int)(q1 >> 32));
        float w2 = __int_as_float((int)(q2 >> 32)), w3 = __int_as_float((int)(q3 >> 32));
        float2 l0 = __half22float2(*(__half2*)&r0.x), h0 = __half22float2(*(__half2*)&r0.y);
        float2 l1 = __half22float2(*(__half2*)&r1.x), h1v = __half22float2(*(__half2*)&r1.y);
        float2 l2 = __half22float2(*(__half2*)&r2.x), h2v = __half22float2(*(__half2*)&r2.y);
        float2 l3 = __half22float2(*(__half2*)&r3.x), h3v = __half22float2(*(__half2*)&r3.y);
        a00 += l0.x * w0; a01 += l0.y * w0; a02 += h0.x * w0; a03 += h0.y * w0;
        a10 += l1.x * w1; a11 += l1.y * w1; a12 += h1v.x * w1; a13 += h1v.y * w1;
        a20 += l2.x * w2; a21 += l2.y * w2; a22 += h2v.x * w2; a23 += h2v.y * w2;
        a30 += l3.x * w3; a31 += l3.y * w3; a32 += h3v.x * w3; a33 += h3v.y * w3;
    }
    for (; j < c; j++) {
        long qq = nt_load_i64(csrl + base + j);
        float2 r = tv[(size_t)((int)qq & 0xFFFFF) * 4 + dq];
        float ww = __int_as_float((int)(qq >> 32));
        float2 l = __half22float2(*(__half2*)&r.x), h = __half22float2(*(__half2*)&r.y);
        a00 += l.x * ww; a01 += l.y * ww; a02 += h.x * ww; a03 += h.y * ww;
    }
    if (valid) {
        float nd = norm_dst[node];
        int d0 = 4 * dq;
        float4 o;
        o.x = ((a00 + a10) + (a20 + a30)) * nd + b2[d0];
        o.y = ((a01 + a11) + (a21 + a31)) * nd + b2[d0 + 1];
        o.z = ((a02 + a12) + (a22 + a32)) * nd + b2[d0 + 2];
        o.w = ((a03 + a13) + (a23 + a33)) * nd + b2[d0 + 3];
        ((float4*)out)[(size_t)node * 4 + dq] = o;
    }
}

extern "C" void kernel_launch(void* const* d_in, const int* in_sizes, int n_in,
                              void* d_out, int out_size, void* d_ws, size_t ws_size,
                              hipStream_t stream) {
    const float* feat = (const float*)d_in[0];
    const int*   src  = (const int*)d_in[1];
    const int*   dst  = (const int*)d_in[2];
    const float* ew   = (const float*)d_in[3];
    const float* W1   = (const float*)d_in[4];
    const float* b1   = (const float*)d_in[5];
    const float* W2   = (const float*)d_in[6];
    const float* b2   = (const float*)d_in[7];
    float* out = (float*)d_out;

    const int n = in_sizes[0] / 32;  // 100000
    const int m = in_sizes[1];       // 1600000

    // ws: pack_part[NB*CAPB int2] | csr[NB*CAPB int2] | h1 half[32n] | h2 half[16n] |
    //     norm_src[n] | norm_dst[n] | rs_cnt int2[n] | g_cur_d[NB] | g_cur_s[NB] |
    //     src_part uchar[NB*CAPB]
    char* wsb = (char*)d_ws;
    int2*   pack_part = (int2*)wsb;
    int2*   csr       = pack_part + (size_t)NB * CAPB;
    __half* h1        = (__half*)(csr + (size_t)NB * CAPB);
    __half* h2        = h1 + 32 * (size_t)n;
    float*  norm_src  = (float*)(h2 + 16 * (size_t)n);
    float*  norm_dst  = norm_src + n;
    int2*   rs_cnt    = (int2*)(norm_dst + n);
    int*    g_cur_d   = (int*)(rs_cnt + n);
    int*    g_cur_s   = g_cur_d + NB;
    unsigned char* src_part = (unsigned char*)(g_cur_s + NB);

    hipMemsetAsync(g_cur_d, 0, 2 * NB * sizeof(int), stream);

    partition_kernel<<<(m + EPB - 1) / EPB, 1024, 0, stream>>>(src, dst, ew, g_cur_d, g_cur_s,
                                                               pack_part, src_part, m);
    csr_kernel<<<NB, 1024, CAPB * sizeof(int2), stream>>>(pack_part, src_part, g_cur_d, g_cur_s,
                                                          feat, W1, csr, rs_cnt,
                                                          norm_src, norm_dst, h1, n);
    gather1_fused_kernel<<<(n + 31) / 32, 256, 0, stream>>>(h1, csr, rs_cnt,
                                                            norm_src, norm_dst, W2, b1, h2, n);
    gather2_kernel<<<(n + 63) / 64, 256, 0, stream>>>(h2, csr, rs_cnt, norm_dst, b2, out, n);
}